// Round 5
// baseline (786.762 us; speedup 1.0000x reference)
//
#include <hip/hip_runtime.h>
#include <stdint.h>

typedef unsigned int u32;
typedef unsigned long long u64;
typedef unsigned short u16;
typedef unsigned char u8;
typedef int intx8 __attribute__((ext_vector_type(8)));
typedef float floatx4 __attribute__((ext_vector_type(4)));

#define BATCH 4096
#define IN    2048
#define HID   8192
#define NCLS  1000

// ---------- ws layout (bytes) ----------
#define OFF_ROWKEY 0u                       // u64[4096]      32 KB (fallback)
#define OFF_TOPK   32768u                   // u64[4096*512]  16 MB
#define OFF_X8     16809984u                // fp8 x           8 MB
#define OFF_WK8    25198592u                // fp8 Wk         16 MB
#define OFF_WGT    41975808u                // fp32 Wg^T   31.25 MB
#define TOTAL_FULL 74743808ull

// ---------- helpers ----------
__device__ __forceinline__ u32 fkey(float f) {          // monotonic float->u32
    u32 u = __float_as_uint(f);
    return (u & 0x80000000u) ? ~u : (u | 0x80000000u);
}
__device__ __forceinline__ float unfkey(u32 k) {
    return __uint_as_float((k & 0x80000000u) ? (k ^ 0x80000000u) : ~k);
}
__device__ __forceinline__ void ce(u64& a, u64& b) {    // desc compare-exchange
    u64 mx = a > b ? a : b;
    u64 mn = a > b ? b : a;
    a = mx; b = mn;
}

// ---------- prep: convert x & Wk to fp8 e4m3 (unit scale), transpose Wg ----------
__global__ __launch_bounds__(256) void prep_kernel(
    const float* __restrict__ x, const float* __restrict__ Wk,
    const float* __restrict__ Wg,
    u8* __restrict__ x8, u8* __restrict__ wk8, float* __restrict__ WgT)
{
    __shared__ float t[32][33];
    const int bid = blockIdx.x;
    if (bid < 1024) {
        // fp8 conversion: segments of 16 floats -> 16 bytes
        const int gid = bid * 256 + threadIdx.x;
        const int NSX = BATCH * IN / 16;          // 524288
        const int NS  = NSX + HID * IN / 16;      // 1572864
        for (int s = gid; s < NS; s += 1024 * 256) {
            const float4* src; u8* dst;
            if (s < NSX) { src = (const float4*)x + (size_t)s * 4;  dst = x8  + (size_t)s * 16; }
            else { int u = s - NSX; src = (const float4*)Wk + (size_t)u * 4; dst = wk8 + (size_t)u * 16; }
            uint4 o;
            float4 f;
            int p;
            f = src[0];
            p = __builtin_amdgcn_cvt_pk_fp8_f32(f.x, f.y, 0, false);
            p = __builtin_amdgcn_cvt_pk_fp8_f32(f.z, f.w, p, true);  o.x = (u32)p;
            f = src[1];
            p = __builtin_amdgcn_cvt_pk_fp8_f32(f.x, f.y, 0, false);
            p = __builtin_amdgcn_cvt_pk_fp8_f32(f.z, f.w, p, true);  o.y = (u32)p;
            f = src[2];
            p = __builtin_amdgcn_cvt_pk_fp8_f32(f.x, f.y, 0, false);
            p = __builtin_amdgcn_cvt_pk_fp8_f32(f.z, f.w, p, true);  o.z = (u32)p;
            f = src[3];
            p = __builtin_amdgcn_cvt_pk_fp8_f32(f.x, f.y, 0, false);
            p = __builtin_amdgcn_cvt_pk_fp8_f32(f.z, f.w, p, true);  o.w = (u32)p;
            *(uint4*)dst = o;
        }
    } else {
        // Wg transpose tile
        const int tb = bid - 1024;
        const int bx = (tb & 255) * 32;   // HID
        const int by = (tb >> 8) * 32;    // NCLS
        const int tx = threadIdx.x & 31, ty = threadIdx.x >> 5;  // ty 0..7
        #pragma unroll
        for (int i = 0; i < 32; i += 8) {
            int c = by + ty + i;
            t[ty + i][tx] = (c < NCLS) ? Wg[(size_t)c * HID + bx + tx] : 0.f;
        }
        __syncthreads();
        #pragma unroll
        for (int i = 0; i < 32; i += 8) {
            int c = by + tx;
            if (c < NCLS) WgT[(size_t)(bx + ty + i) * NCLS + by + tx] = t[tx][ty + i];
        }
    }
}

// ---------- fp8 MFMA GEMM (16x16x128, unit scales): top-4 per (row, 64-col group) ----------
// 128x128 tile, BK=128, 4 waves, each wave owns a 64x64 quadrant (4x4 MFMA tiles).
// LDS is plain row-major [row][128]; fragments are CONTIGUOUS 32B loads so LLVM
// forms the v8i32 MFMA operand from two adjacent ds_read_b128 with no v_mov copies
// (round-4's swizzled split loads doubled fragment VGPRs -> 256-reg spill cliff).
__global__ __launch_bounds__(256, 3) void mfma_fp8_gemm_kernel(
    const u8* __restrict__ x8, const u8* __restrict__ wk8,
    u64* __restrict__ topk)
{
    __shared__ __align__(16) u8 At[128 * 128];   // 16 KB
    __shared__ __align__(16) u8 Bt[128 * 128];   // 16 KB

    const int tid  = threadIdx.x;
    const int lane = tid & 63;
    const int w    = tid >> 6;
    const int bm   = blockIdx.y * 128;
    const int bn   = blockIdx.x * 128;
    const int wrow = (w >> 1) * 64, wcol = (w & 1) * 64;
    const int m = lane & 15, q = lane >> 4;

    floatx4 acc[4][4];
    #pragma unroll
    for (int i = 0; i < 4; i++)
        #pragma unroll
        for (int j = 0; j < 4; j++)
            acc[i][j] = (floatx4){0.f, 0.f, 0.f, 0.f};

    // staging: thread covers row (tid>>3), 16B-chunk (tid&7); 4 issues cover 128 rows
    const int srow = tid >> 3;
    const int soff = (tid & 7) * 16;
    const u8* gA[4];
    const u8* gB[4];
    #pragma unroll
    for (int s = 0; s < 4; s++) {
        gA[s] = x8  + (size_t)(bm + s * 32 + srow) * IN + soff;
        gB[s] = wk8 + (size_t)(bn + s * 32 + srow) * IN + soff;
    }

    for (int k0 = 0; k0 < IN; k0 += 128) {
        #pragma unroll
        for (int s = 0; s < 4; s++) {
            __builtin_amdgcn_global_load_lds(
                (const __attribute__((address_space(1))) u32*)(gA[s] + k0),
                (__attribute__((address_space(3))) u32*)&At[s * 4096 + tid * 16], 16, 0, 0);
            __builtin_amdgcn_global_load_lds(
                (const __attribute__((address_space(1))) u32*)(gB[s] + k0),
                (__attribute__((address_space(3))) u32*)&Bt[s * 4096 + tid * 16], 16, 0, 0);
        }
        __syncthreads();   // staging complete

        intx8 af[4];
        #pragma unroll
        for (int i = 0; i < 4; i++)
            af[i] = *(const intx8*)&At[(wrow + i * 16 + m) * 128 + q * 32];
        #pragma unroll
        for (int j = 0; j < 4; j++) {
            intx8 bf = *(const intx8*)&Bt[(wcol + j * 16 + m) * 128 + q * 32];
            #pragma unroll
            for (int i = 0; i < 4; i++)
                acc[i][j] = __builtin_amdgcn_mfma_scale_f32_16x16x128_f8f6f4(
                    af[i], bf, acc[i][j],
                    0, 0,            // cbsz=FP8(e4m3), blgp=FP8(e4m3)
                    0, 0x7F,         // opsel_a, scale_a = 2^0
                    0, 0x7F);        // opsel_b, scale_b = 2^0
        }

        __syncthreads();   // reads done before next overwrite
    }

    // epilogue: per-row top-4 over this wave's 64 columns (butterfly bitonic merge)
    const int g4 = (blockIdx.x * 2 + (wcol >> 6)) * 4;   // group slot base, 0..508
    #pragma unroll
    for (int i = 0; i < 4; i++) {
        #pragma unroll
        for (int r = 0; r < 4; r++) {
            u64 k0, k1, k2, k3;
            {
                const int c0 = bn + wcol + 0 * 16 + m;
                const int c1 = bn + wcol + 1 * 16 + m;
                const int c2 = bn + wcol + 2 * 16 + m;
                const int c3 = bn + wcol + 3 * 16 + m;
                k0 = ((u64)fkey(acc[i][0][r]) << 32) | (u64)(0x1FFFu - (u32)c0);
                k1 = ((u64)fkey(acc[i][1][r]) << 32) | (u64)(0x1FFFu - (u32)c1);
                k2 = ((u64)fkey(acc[i][2][r]) << 32) | (u64)(0x1FFFu - (u32)c2);
                k3 = ((u64)fkey(acc[i][3][r]) << 32) | (u64)(0x1FFFu - (u32)c3);
            }
            // sort 4 desc
            ce(k0, k1); ce(k2, k3); ce(k0, k2); ce(k1, k3); ce(k1, k2);
            #pragma unroll
            for (int off = 1; off < 16; off <<= 1) {
                u64 b0 = __shfl_xor(k0, off, 64);
                u64 b1 = __shfl_xor(k1, off, 64);
                u64 b2 = __shfl_xor(k2, off, 64);
                u64 b3 = __shfl_xor(k3, off, 64);
                k0 = k0 > b3 ? k0 : b3;        // bitonic CE (i, i+4), keep max
                k1 = k1 > b2 ? k1 : b2;
                k2 = k2 > b1 ? k2 : b1;
                k3 = k3 > b0 ? k3 : b0;
                ce(k0, k2); ce(k1, k3); ce(k0, k1); ce(k2, k3);  // sort bitonic 4
            }
            if (m == 0) {
                const int grow = bm + wrow + i * 16 + q * 4 + r;
                ulonglong2 v01; v01.x = k0; v01.y = k1;
                ulonglong2 v23; v23.x = k2; v23.y = k3;
                *(ulonglong2*)&topk[(size_t)grow * 512 + g4]     = v01;
                *(ulonglong2*)&topk[(size_t)grow * 512 + g4 + 2] = v23;
            }
        }
    }
}

// ---------- scan top-4 keys, exact fp32 rescore of near-max, fused gather ----------
__global__ __launch_bounds__(256) void scan_kernel(
    const u64* __restrict__ topk,
    const float* __restrict__ x, const float* __restrict__ Wk,
    const float* __restrict__ WgT, float* __restrict__ out)
{
    __shared__ u64 wmax[4];
    __shared__ int cnt;
    __shared__ u64 candk[128];
    __shared__ u64 bestk;
    const int row  = blockIdx.x;
    const int tid  = threadIdx.x;
    const int lane = tid & 63;
    const int w    = tid >> 6;
    if (tid == 0) { cnt = 0; bestk = 0ull; }

    ulonglong2 kk = *(const ulonglong2*)&topk[(size_t)row * 512 + tid * 2];
    u64 mx = kk.x > kk.y ? kk.x : kk.y;
    #pragma unroll
    for (int off = 1; off < 64; off <<= 1) {
        u64 o = __shfl_xor(mx, off, 64);
        if (o > mx) mx = o;
    }
    if (lane == 0) wmax[w] = mx;
    __syncthreads();                 // also orders cnt/bestk init
    u64 gmax = wmax[0];
    #pragma unroll
    for (int i = 1; i < 4; i++) if (wmax[i] > gmax) gmax = wmax[i];

    // screen window: fp8-input GEMM error sigma ~1.3; 12.0 ~ 6.4 sigma of the diff
    const float thr = unfkey((u32)(gmax >> 32)) - 12.0f;
    if (unfkey((u32)(kk.x >> 32)) >= thr) { int c = atomicAdd(&cnt, 1); if (c < 128) candk[c] = kk.x; }
    if (unfkey((u32)(kk.y >> 32)) >= thr) { int c = atomicAdd(&cnt, 1); if (c < 128) candk[c] = kk.y; }
    __syncthreads();
    const int n = min(cnt, 128);

    int col;
    if (n <= 1) {
        col = 0x1FFF - (int)(gmax & 0xFFFFu);
    } else {
        // wave-parallel exact rescore
        const float4* xr = (const float4*)(x + (size_t)row * IN);
        for (int c = w; c < n; c += 4) {
            const int h = 0x1FFF - (int)(candk[c] & 0xFFFFu);
            const float4* wr = (const float4*)(Wk + (size_t)h * IN);
            float p = 0.f;
            #pragma unroll
            for (int pass = 0; pass < 8; pass++) {
                float4 a = xr[pass * 64 + lane];
                float4 b = wr[pass * 64 + lane];
                p += a.x * b.x + a.y * b.y + a.z * b.z + a.w * b.w;
            }
            #pragma unroll
            for (int off = 1; off < 64; off <<= 1) p += __shfl_xor(p, off, 64);
            if (lane == 0) {
                u64 key = ((u64)fkey(p) << 32) | (u64)(0x1FFFu - (u32)h);
                atomicMax(&bestk, key);
            }
        }
        __syncthreads();
        col = 0x1FFF - (int)(bestk & 0xFFFFu);
    }

    // fused gather: out[row, :] = WgT[col, :]
    const float* src = WgT + (size_t)col * NCLS;
    for (int c = tid; c < NCLS; c += 256)
        out[(size_t)row * NCLS + c] = src[c];
}

// ---------- round-1 fp32 fallback (used only if ws too small) ----------
__global__ void init_ws_kernel(u64* rowkey) {
    int i = blockIdx.x * blockDim.x + threadIdx.x;
    if (i < BATCH) rowkey[i] = 0ULL;
}

__global__ __launch_bounds__(256) void gemm_argmax_kernel(
    const float* __restrict__ x, const float* __restrict__ Wk,
    u64* __restrict__ rowkey)
{
    __shared__ __align__(16) float As[32 * 64];
    __shared__ __align__(16) float Bs[32 * 64];
    const int tid = threadIdx.x;
    const int bm = blockIdx.y * 64, bn = blockIdx.x * 64;
    const int tx = tid & 15, ty = tid >> 4;
    float acc[4][4];
    #pragma unroll
    for (int i = 0; i < 4; i++)
        #pragma unroll
        for (int j = 0; j < 4; j++) acc[i][j] = 0.f;
    const int r0 = tid >> 3, q0 = tid & 7;
    const int r1 = (tid + 256) >> 3, q1 = (tid + 256) & 7;
    const float* xA0 = &x[(size_t)(bm + r0) * IN + q0 * 4];
    const float* xA1 = &x[(size_t)(bm + r1) * IN + q1 * 4];
    const float* wB0 = &Wk[(size_t)(bn + r0) * IN + q0 * 4];
    const float* wB1 = &Wk[(size_t)(bn + r1) * IN + q1 * 4];
    for (int k0 = 0; k0 < IN; k0 += 32) {
        float4 a0 = *(const float4*)(xA0 + k0);
        float4 a1 = *(const float4*)(xA1 + k0);
        float4 b0 = *(const float4*)(wB0 + k0);
        float4 b1 = *(const float4*)(wB1 + k0);
        __syncthreads();
        As[(q0 * 4 + 0) * 64 + r0] = a0.x; As[(q0 * 4 + 1) * 64 + r0] = a0.y;
        As[(q0 * 4 + 2) * 64 + r0] = a0.z; As[(q0 * 4 + 3) * 64 + r0] = a0.w;
        As[(q1 * 4 + 0) * 64 + r1] = a1.x; As[(q1 * 4 + 1) * 64 + r1] = a1.y;
        As[(q1 * 4 + 2) * 64 + r1] = a1.z; As[(q1 * 4 + 3) * 64 + r1] = a1.w;
        Bs[(q0 * 4 + 0) * 64 + r0] = b0.x; Bs[(q0 * 4 + 1) * 64 + r0] = b0.y;
        Bs[(q0 * 4 + 2) * 64 + r0] = b0.z; Bs[(q0 * 4 + 3) * 64 + r0] = b0.w;
        Bs[(q1 * 4 + 0) * 64 + r1] = b1.x; Bs[(q1 * 4 + 1) * 64 + r1] = b1.y;
        Bs[(q1 * 4 + 2) * 64 + r1] = b1.z; Bs[(q1 * 4 + 3) * 64 + r1] = b1.w;
        __syncthreads();
        #pragma unroll
        for (int k = 0; k < 32; k++) {
            float4 av = *(const float4*)&As[k * 64 + ty * 4];
            float4 bv = *(const float4*)&Bs[k * 64 + tx * 4];
            acc[0][0] += av.x * bv.x; acc[0][1] += av.x * bv.y;
            acc[0][2] += av.x * bv.z; acc[0][3] += av.x * bv.w;
            acc[1][0] += av.y * bv.x; acc[1][1] += av.y * bv.y;
            acc[1][2] += av.y * bv.z; acc[1][3] += av.y * bv.w;
            acc[2][0] += av.z * bv.x; acc[2][1] += av.z * bv.y;
            acc[2][2] += av.z * bv.z; acc[2][3] += av.z * bv.w;
            acc[3][0] += av.w * bv.x; acc[3][1] += av.w * bv.y;
            acc[3][2] += av.w * bv.z; acc[3][3] += av.w * bv.w;
        }
    }
    #pragma unroll
    for (int i = 0; i < 4; i++) {
        const int row = bm + ty * 4 + i;
        u64 best = 0ULL;
        #pragma unroll
        for (int j = 0; j < 4; j++) {
            const int col = bn + tx * 4 + j;
            u64 p = ((u64)fkey(acc[i][j]) << 32) | (u64)(0x1FFFu - (unsigned)col);
            if (p > best) best = p;
        }
        #pragma unroll
        for (int off = 1; off < 16; off <<= 1) {
            u64 other = __shfl_xor(best, off, 64);
            if (other > best) best = other;
        }
        if (tx == 0) atomicMax(&rowkey[row], best);
    }
}

__global__ __launch_bounds__(256) void gather_kernel(
    const u64* __restrict__ rowkey, const float* __restrict__ Wg,
    float* __restrict__ out)
{
    const int b = blockIdx.y;
    const int c = blockIdx.x * 256 + threadIdx.x;
    if (c >= NCLS) return;
    const int col = 0x1FFF - (int)(rowkey[b] & 0xFFFFFFFFu);
    out[(size_t)b * NCLS + c] = Wg[(size_t)c * HID + col];
}

// ---------- launch ----------
extern "C" void kernel_launch(void* const* d_in, const int* in_sizes, int n_in,
                              void* d_out, int out_size, void* d_ws, size_t ws_size,
                              hipStream_t stream) {
    const float* x  = (const float*)d_in[0];
    const float* Wk = (const float*)d_in[1];
    const float* Wg = (const float*)d_in[2];
    float* out = (float*)d_out;
    char* ws = (char*)d_ws;

    if (ws_size >= TOTAL_FULL) {
        u64* topk  = (u64*)(ws + OFF_TOPK);
        u8*  x8    = (u8*)(ws + OFF_X8);
        u8*  wk8   = (u8*)(ws + OFF_WK8);
        float* WgT = (float*)(ws + OFF_WGT);

        hipLaunchKernelGGL(prep_kernel, dim3(1024 + 8192), dim3(256), 0, stream,
                           x, Wk, Wg, x8, wk8, WgT);
        hipLaunchKernelGGL(mfma_fp8_gemm_kernel, dim3(HID / 128, BATCH / 128), dim3(256), 0, stream,
                           x8, wk8, topk);
        hipLaunchKernelGGL(scan_kernel, dim3(BATCH), dim3(256), 0, stream,
                           topk, x, Wk, WgT, out);
    } else {
        u64* rowkey = (u64*)(ws + OFF_ROWKEY);
        hipLaunchKernelGGL(init_ws_kernel, dim3(16), dim3(256), 0, stream, rowkey);
        hipLaunchKernelGGL(gemm_argmax_kernel, dim3(HID / 64, BATCH / 64), dim3(256), 0, stream,
                           x, Wk, rowkey);
        hipLaunchKernelGGL(gather_kernel, dim3(4, BATCH), dim3(256), 0, stream,
                           rowkey, Wg, out);
    }
}

// Round 6
// 317.578 us; speedup vs baseline: 2.4774x; 2.4774x over previous
//
#include <hip/hip_runtime.h>
#include <stdint.h>

typedef unsigned int u32;
typedef unsigned long long u64;
typedef unsigned short u16;
typedef unsigned char u8;
typedef int intx8 __attribute__((ext_vector_type(8)));
typedef float floatx4 __attribute__((ext_vector_type(4)));

#define BATCH 4096
#define IN    2048
#define HID   8192
#define NCLS  1000

// ---------- ws layout (bytes) ----------
#define OFF_ROWKEY 0u                       // u64[4096]      32 KB (fallback)
#define OFF_TOPK   32768u                   // u64[4096*512]  16 MB
#define OFF_X8     16809984u                // fp8 x           8 MB
#define OFF_WK8    25198592u                // fp8 Wk         16 MB
#define OFF_WGT    41975808u                // fp32 Wg^T   31.25 MB
#define TOTAL_FULL 74743808ull

// ---------- helpers ----------
__device__ __forceinline__ u32 fkey(float f) {          // monotonic float->u32
    u32 u = __float_as_uint(f);
    return (u & 0x80000000u) ? ~u : (u | 0x80000000u);
}
__device__ __forceinline__ float unfkey(u32 k) {
    return __uint_as_float((k & 0x80000000u) ? (k ^ 0x80000000u) : ~k);
}
__device__ __forceinline__ void ce(u64& a, u64& b) {    // desc compare-exchange
    u64 mx = a > b ? a : b;
    u64 mn = a > b ? b : a;
    a = mx; b = mn;
}

// ---------- prep: convert x & Wk to fp8 e4m3 (unit scale), transpose Wg ----------
__global__ __launch_bounds__(256) void prep_kernel(
    const float* __restrict__ x, const float* __restrict__ Wk,
    const float* __restrict__ Wg,
    u8* __restrict__ x8, u8* __restrict__ wk8, float* __restrict__ WgT)
{
    __shared__ float t[32][33];
    const int bid = blockIdx.x;
    if (bid < 1024) {
        // fp8 conversion: segments of 16 floats -> 16 bytes
        const int gid = bid * 256 + threadIdx.x;
        const int NSX = BATCH * IN / 16;          // 524288
        const int NS  = NSX + HID * IN / 16;      // 1572864
        for (int s = gid; s < NS; s += 1024 * 256) {
            const float4* src; u8* dst;
            if (s < NSX) { src = (const float4*)x + (size_t)s * 4;  dst = x8  + (size_t)s * 16; }
            else { int u = s - NSX; src = (const float4*)Wk + (size_t)u * 4; dst = wk8 + (size_t)u * 16; }
            uint4 o;
            float4 f;
            int p;
            f = src[0];
            p = __builtin_amdgcn_cvt_pk_fp8_f32(f.x, f.y, 0, false);
            p = __builtin_amdgcn_cvt_pk_fp8_f32(f.z, f.w, p, true);  o.x = (u32)p;
            f = src[1];
            p = __builtin_amdgcn_cvt_pk_fp8_f32(f.x, f.y, 0, false);
            p = __builtin_amdgcn_cvt_pk_fp8_f32(f.z, f.w, p, true);  o.y = (u32)p;
            f = src[2];
            p = __builtin_amdgcn_cvt_pk_fp8_f32(f.x, f.y, 0, false);
            p = __builtin_amdgcn_cvt_pk_fp8_f32(f.z, f.w, p, true);  o.z = (u32)p;
            f = src[3];
            p = __builtin_amdgcn_cvt_pk_fp8_f32(f.x, f.y, 0, false);
            p = __builtin_amdgcn_cvt_pk_fp8_f32(f.z, f.w, p, true);  o.w = (u32)p;
            *(uint4*)dst = o;
        }
    } else {
        // Wg transpose tile
        const int tb = bid - 1024;
        const int bx = (tb & 255) * 32;   // HID
        const int by = (tb >> 8) * 32;    // NCLS
        const int tx = threadIdx.x & 31, ty = threadIdx.x >> 5;  // ty 0..7
        #pragma unroll
        for (int i = 0; i < 32; i += 8) {
            int c = by + ty + i;
            t[ty + i][tx] = (c < NCLS) ? Wg[(size_t)c * HID + bx + tx] : 0.f;
        }
        __syncthreads();
        #pragma unroll
        for (int i = 0; i < 32; i += 8) {
            int c = by + tx;
            if (c < NCLS) WgT[(size_t)(bx + ty + i) * NCLS + by + tx] = t[tx][ty + i];
        }
    }
}

// ---------- fp8 MFMA GEMM (16x16x128, unit scales): top-4 per (row, 64-col group) ----------
// 128x128 tile, BK=128, 4 waves, each wave owns a 64x64 quadrant (4x4 MFMA tiles).
// LDS swizzle: physical 32B granule P of row r holds logical granule P^(r&3).
// - staging: each lane's SOURCE offset is permuted (LDS dst fixed at lane*16);
// - fragments: ONE contiguous 32B load at row*128 + (q^(m&3))*32 -> two adjacent
//   ds_read_b128, no cross-register shuffling (keeps VGPRs low — r4 lesson);
// - bank spread: fragment-read phase hits 4 distinct bank-quads (4-way, 1.58x)
//   instead of r5's 16-way pile-up on one quad.
// No __launch_bounds__ occupancy pin: r5's (256,3) cap forced per-iteration
// fragment spill (1 GB scratch traffic). Let the allocator size itself.
__global__ __launch_bounds__(256) void mfma_fp8_gemm_kernel(
    const u8* __restrict__ x8, const u8* __restrict__ wk8,
    u64* __restrict__ topk)
{
    __shared__ __align__(16) u8 At[128 * 128];   // 16 KB
    __shared__ __align__(16) u8 Bt[128 * 128];   // 16 KB

    const int tid  = threadIdx.x;
    const int lane = tid & 63;
    const int w    = tid >> 6;
    const int bm   = blockIdx.y * 128;
    const int bn   = blockIdx.x * 128;
    const int wrow = (w >> 1) * 64, wcol = (w & 1) * 64;
    const int m = lane & 15, q = lane >> 4;

    floatx4 acc[4][4];
    #pragma unroll
    for (int i = 0; i < 4; i++)
        #pragma unroll
        for (int j = 0; j < 4; j++)
            acc[i][j] = (floatx4){0.f, 0.f, 0.f, 0.f};

    // staging: lane covers row (tid>>3); source 16B-chunk permuted so that
    // physical chunk (tid&7) = logical granule ((tid>>1)&3)^(row&3), half (tid&1)
    const int srow = tid >> 3;
    const int soff = (((((tid >> 1) & 3) ^ (srow & 3)) * 2) + (tid & 1)) * 16;
    const u8* gxa = x8  + (size_t)(bm + srow) * IN + soff;
    const u8* gwb = wk8 + (size_t)(bn + srow) * IN + soff;

    // fragment read offset: logical granule q of row (..+m) sits at q^(m&3)
    const int foq = (q ^ (m & 3)) * 32;

    #pragma unroll 1
    for (int k0 = 0; k0 < IN; k0 += 128) {
        #pragma unroll
        for (int s = 0; s < 4; s++) {
            __builtin_amdgcn_global_load_lds(
                (const __attribute__((address_space(1))) u32*)(gxa + k0 + (size_t)s * 32 * IN),
                (__attribute__((address_space(3))) u32*)&At[s * 4096 + tid * 16], 16, 0, 0);
            __builtin_amdgcn_global_load_lds(
                (const __attribute__((address_space(1))) u32*)(gwb + k0 + (size_t)s * 32 * IN),
                (__attribute__((address_space(3))) u32*)&Bt[s * 4096 + tid * 16], 16, 0, 0);
        }
        __syncthreads();   // staging complete

        intx8 af[4];
        #pragma unroll
        for (int i = 0; i < 4; i++)
            af[i] = *(const intx8*)&At[(wrow + i * 16 + m) * 128 + foq];
        #pragma unroll
        for (int j = 0; j < 4; j++) {
            intx8 bf = *(const intx8*)&Bt[(wcol + j * 16 + m) * 128 + foq];
            #pragma unroll
            for (int i = 0; i < 4; i++)
                acc[i][j] = __builtin_amdgcn_mfma_scale_f32_16x16x128_f8f6f4(
                    af[i], bf, acc[i][j],
                    0, 0,            // cbsz=FP8(e4m3), blgp=FP8(e4m3)
                    0, 0x7F,         // opsel_a, scale_a = 2^0
                    0, 0x7F);        // opsel_b, scale_b = 2^0
        }

        __syncthreads();   // reads done before next overwrite
    }

    // epilogue: per-row top-4 over this wave's 64 columns (butterfly bitonic merge)
    const int g4 = (blockIdx.x * 2 + (wcol >> 6)) * 4;   // group slot base, 0..508
    #pragma unroll
    for (int i = 0; i < 4; i++) {
        #pragma unroll
        for (int r = 0; r < 4; r++) {
            u64 k0, k1, k2, k3;
            {
                const int c0 = bn + wcol + 0 * 16 + m;
                const int c1 = bn + wcol + 1 * 16 + m;
                const int c2 = bn + wcol + 2 * 16 + m;
                const int c3 = bn + wcol + 3 * 16 + m;
                k0 = ((u64)fkey(acc[i][0][r]) << 32) | (u64)(0x1FFFu - (u32)c0);
                k1 = ((u64)fkey(acc[i][1][r]) << 32) | (u64)(0x1FFFu - (u32)c1);
                k2 = ((u64)fkey(acc[i][2][r]) << 32) | (u64)(0x1FFFu - (u32)c2);
                k3 = ((u64)fkey(acc[i][3][r]) << 32) | (u64)(0x1FFFu - (u32)c3);
            }
            // sort 4 desc
            ce(k0, k1); ce(k2, k3); ce(k0, k2); ce(k1, k3); ce(k1, k2);
            #pragma unroll
            for (int off = 1; off < 16; off <<= 1) {
                u64 b0 = __shfl_xor(k0, off, 64);
                u64 b1 = __shfl_xor(k1, off, 64);
                u64 b2 = __shfl_xor(k2, off, 64);
                u64 b3 = __shfl_xor(k3, off, 64);
                k0 = k0 > b3 ? k0 : b3;        // bitonic CE (i, i+4), keep max
                k1 = k1 > b2 ? k1 : b2;
                k2 = k2 > b1 ? k2 : b1;
                k3 = k3 > b0 ? k3 : b0;
                ce(k0, k2); ce(k1, k3); ce(k0, k1); ce(k2, k3);  // sort bitonic 4
            }
            if (m == 0) {
                const int grow = bm + wrow + i * 16 + q * 4 + r;
                ulonglong2 v01; v01.x = k0; v01.y = k1;
                ulonglong2 v23; v23.x = k2; v23.y = k3;
                *(ulonglong2*)&topk[(size_t)grow * 512 + g4]     = v01;
                *(ulonglong2*)&topk[(size_t)grow * 512 + g4 + 2] = v23;
            }
        }
    }
}

// ---------- scan top-4 keys, exact fp32 rescore of near-max, fused gather ----------
__global__ __launch_bounds__(256) void scan_kernel(
    const u64* __restrict__ topk,
    const float* __restrict__ x, const float* __restrict__ Wk,
    const float* __restrict__ WgT, float* __restrict__ out)
{
    __shared__ u64 wmax[4];
    __shared__ int cnt;
    __shared__ u64 candk[128];
    __shared__ u64 bestk;
    const int row  = blockIdx.x;
    const int tid  = threadIdx.x;
    const int lane = tid & 63;
    const int w    = tid >> 6;
    if (tid == 0) { cnt = 0; bestk = 0ull; }

    ulonglong2 kk = *(const ulonglong2*)&topk[(size_t)row * 512 + tid * 2];
    u64 mx = kk.x > kk.y ? kk.x : kk.y;
    #pragma unroll
    for (int off = 1; off < 64; off <<= 1) {
        u64 o = __shfl_xor(mx, off, 64);
        if (o > mx) mx = o;
    }
    if (lane == 0) wmax[w] = mx;
    __syncthreads();                 // also orders cnt/bestk init
    u64 gmax = wmax[0];
    #pragma unroll
    for (int i = 1; i < 4; i++) if (wmax[i] > gmax) gmax = wmax[i];

    // screen window: fp8-input GEMM error sigma ~1.3; 12.0 ~ 6.4 sigma of the diff
    const float thr = unfkey((u32)(gmax >> 32)) - 12.0f;
    if (unfkey((u32)(kk.x >> 32)) >= thr) { int c = atomicAdd(&cnt, 1); if (c < 128) candk[c] = kk.x; }
    if (unfkey((u32)(kk.y >> 32)) >= thr) { int c = atomicAdd(&cnt, 1); if (c < 128) candk[c] = kk.y; }
    __syncthreads();
    const int n = min(cnt, 128);

    int col;
    if (n <= 1) {
        col = 0x1FFF - (int)(gmax & 0xFFFFu);
    } else {
        // wave-parallel exact rescore
        const float4* xr = (const float4*)(x + (size_t)row * IN);
        for (int c = w; c < n; c += 4) {
            const int h = 0x1FFF - (int)(candk[c] & 0xFFFFu);
            const float4* wr = (const float4*)(Wk + (size_t)h * IN);
            float p = 0.f;
            #pragma unroll
            for (int pass = 0; pass < 8; pass++) {
                float4 a = xr[pass * 64 + lane];
                float4 b = wr[pass * 64 + lane];
                p += a.x * b.x + a.y * b.y + a.z * b.z + a.w * b.w;
            }
            #pragma unroll
            for (int off = 1; off < 64; off <<= 1) p += __shfl_xor(p, off, 64);
            if (lane == 0) {
                u64 key = ((u64)fkey(p) << 32) | (u64)(0x1FFFu - (u32)h);
                atomicMax(&bestk, key);
            }
        }
        __syncthreads();
        col = 0x1FFF - (int)(bestk & 0xFFFFu);
    }

    // fused gather: out[row, :] = WgT[col, :]
    const float* src = WgT + (size_t)col * NCLS;
    for (int c = tid; c < NCLS; c += 256)
        out[(size_t)row * NCLS + c] = src[c];
}

// ---------- round-1 fp32 fallback (used only if ws too small) ----------
__global__ void init_ws_kernel(u64* rowkey) {
    int i = blockIdx.x * blockDim.x + threadIdx.x;
    if (i < BATCH) rowkey[i] = 0ULL;
}

__global__ __launch_bounds__(256) void gemm_argmax_kernel(
    const float* __restrict__ x, const float* __restrict__ Wk,
    u64* __restrict__ rowkey)
{
    __shared__ __align__(16) float As[32 * 64];
    __shared__ __align__(16) float Bs[32 * 64];
    const int tid = threadIdx.x;
    const int bm = blockIdx.y * 64, bn = blockIdx.x * 64;
    const int tx = tid & 15, ty = tid >> 4;
    float acc[4][4];
    #pragma unroll
    for (int i = 0; i < 4; i++)
        #pragma unroll
        for (int j = 0; j < 4; j++) acc[i][j] = 0.f;
    const int r0 = tid >> 3, q0 = tid & 7;
    const int r1 = (tid + 256) >> 3, q1 = (tid + 256) & 7;
    const float* xA0 = &x[(size_t)(bm + r0) * IN + q0 * 4];
    const float* xA1 = &x[(size_t)(bm + r1) * IN + q1 * 4];
    const float* wB0 = &Wk[(size_t)(bn + r0) * IN + q0 * 4];
    const float* wB1 = &Wk[(size_t)(bn + r1) * IN + q1 * 4];
    for (int k0 = 0; k0 < IN; k0 += 32) {
        float4 a0 = *(const float4*)(xA0 + k0);
        float4 a1 = *(const float4*)(xA1 + k0);
        float4 b0 = *(const float4*)(wB0 + k0);
        float4 b1 = *(const float4*)(wB1 + k0);
        __syncthreads();
        As[(q0 * 4 + 0) * 64 + r0] = a0.x; As[(q0 * 4 + 1) * 64 + r0] = a0.y;
        As[(q0 * 4 + 2) * 64 + r0] = a0.z; As[(q0 * 4 + 3) * 64 + r0] = a0.w;
        As[(q1 * 4 + 0) * 64 + r1] = a1.x; As[(q1 * 4 + 1) * 64 + r1] = a1.y;
        As[(q1 * 4 + 2) * 64 + r1] = a1.z; As[(q1 * 4 + 3) * 64 + r1] = a1.w;
        Bs[(q0 * 4 + 0) * 64 + r0] = b0.x; Bs[(q0 * 4 + 1) * 64 + r0] = b0.y;
        Bs[(q0 * 4 + 2) * 64 + r0] = b0.z; Bs[(q0 * 4 + 3) * 64 + r0] = b0.w;
        Bs[(q1 * 4 + 0) * 64 + r1] = b1.x; Bs[(q1 * 4 + 1) * 64 + r1] = b1.y;
        Bs[(q1 * 4 + 2) * 64 + r1] = b1.z; Bs[(q1 * 4 + 3) * 64 + r1] = b1.w;
        __syncthreads();
        #pragma unroll
        for (int k = 0; k < 32; k++) {
            float4 av = *(const float4*)&As[k * 64 + ty * 4];
            float4 bv = *(const float4*)&Bs[k * 64 + tx * 4];
            acc[0][0] += av.x * bv.x; acc[0][1] += av.x * bv.y;
            acc[0][2] += av.x * bv.z; acc[0][3] += av.x * bv.w;
            acc[1][0] += av.y * bv.x; acc[1][1] += av.y * bv.y;
            acc[1][2] += av.y * bv.z; acc[1][3] += av.y * bv.w;
            acc[2][0] += av.z * bv.x; acc[2][1] += av.z * bv.y;
            acc[2][2] += av.z * bv.z; acc[2][3] += av.z * bv.w;
            acc[3][0] += av.w * bv.x; acc[3][1] += av.w * bv.y;
            acc[3][2] += av.w * bv.z; acc[3][3] += av.w * bv.w;
        }
    }
    #pragma unroll
    for (int i = 0; i < 4; i++) {
        const int row = bm + ty * 4 + i;
        u64 best = 0ULL;
        #pragma unroll
        for (int j = 0; j < 4; j++) {
            const int col = bn + tx * 4 + j;
            u64 p = ((u64)fkey(acc[i][j]) << 32) | (u64)(0x1FFFu - (unsigned)col);
            if (p > best) best = p;
        }
        #pragma unroll
        for (int off = 1; off < 16; off <<= 1) {
            u64 other = __shfl_xor(best, off, 64);
            if (other > best) best = other;
        }
        if (tx == 0) atomicMax(&rowkey[row], best);
    }
}

__global__ __launch_bounds__(256) void gather_kernel(
    const u64* __restrict__ rowkey, const float* __restrict__ Wg,
    float* __restrict__ out)
{
    const int b = blockIdx.y;
    const int c = blockIdx.x * 256 + threadIdx.x;
    if (c >= NCLS) return;
    const int col = 0x1FFF - (int)(rowkey[b] & 0xFFFFFFFFu);
    out[(size_t)b * NCLS + c] = Wg[(size_t)c * HID + col];
}

// ---------- launch ----------
extern "C" void kernel_launch(void* const* d_in, const int* in_sizes, int n_in,
                              void* d_out, int out_size, void* d_ws, size_t ws_size,
                              hipStream_t stream) {
    const float* x  = (const float*)d_in[0];
    const float* Wk = (const float*)d_in[1];
    const float* Wg = (const float*)d_in[2];
    float* out = (float*)d_out;
    char* ws = (char*)d_ws;

    if (ws_size >= TOTAL_FULL) {
        u64* topk  = (u64*)(ws + OFF_TOPK);
        u8*  x8    = (u8*)(ws + OFF_X8);
        u8*  wk8   = (u8*)(ws + OFF_WK8);
        float* WgT = (float*)(ws + OFF_WGT);

        hipLaunchKernelGGL(prep_kernel, dim3(1024 + 8192), dim3(256), 0, stream,
                           x, Wk, Wg, x8, wk8, WgT);
        hipLaunchKernelGGL(mfma_fp8_gemm_kernel, dim3(HID / 128, BATCH / 128), dim3(256), 0, stream,
                           x8, wk8, topk);
        hipLaunchKernelGGL(scan_kernel, dim3(BATCH), dim3(256), 0, stream,
                           topk, x, Wk, WgT, out);
    } else {
        u64* rowkey = (u64*)(ws + OFF_ROWKEY);
        hipLaunchKernelGGL(init_ws_kernel, dim3(16), dim3(256), 0, stream, rowkey);
        hipLaunchKernelGGL(gemm_argmax_kernel, dim3(HID / 64, BATCH / 64), dim3(256), 0, stream,
                           x, Wk, rowkey);
        hipLaunchKernelGGL(gather_kernel, dim3(4, BATCH), dim3(256), 0, stream,
                           rowkey, Wg, out);
    }
}

// Round 7
// 310.319 us; speedup vs baseline: 2.5353x; 1.0234x over previous
//
#include <hip/hip_runtime.h>
#include <stdint.h>

typedef unsigned int u32;
typedef unsigned long long u64;
typedef unsigned short u16;
typedef unsigned char u8;
typedef int intx8 __attribute__((ext_vector_type(8)));
typedef float floatx4 __attribute__((ext_vector_type(4)));

#define BATCH 4096
#define IN    2048
#define HID   8192
#define NCLS  1000

// ---------- ws layout (bytes) ----------
#define OFF_ROWKEY 0u                       // u64[4096]      32 KB (fallback)
#define OFF_TOPK   32768u                   // u32[4096*512]   8 MB
#define OFF_X8     8421376u                 // fp8 x           8 MB
#define OFF_WK8    16809984u                // fp8 Wk         16 MB
#define OFF_WGT    33587200u                // fp32 Wg^T   31.25 MB
#define TOTAL_FULL 66355200ull

// ---------- helpers ----------
__device__ __forceinline__ u32 fkey(float f) {          // monotonic float->u32
    u32 u = __float_as_uint(f);
    return (u & 0x80000000u) ? ~u : (u | 0x80000000u);
}
__device__ __forceinline__ float unfkey(u32 k) {
    return __uint_as_float((k & 0x80000000u) ? (k ^ 0x80000000u) : ~k);
}
__device__ __forceinline__ void ce32(u32& a, u32& b) {  // desc compare-exchange (2 ops)
    u32 mx = a > b ? a : b;
    u32 mn = a > b ? b : a;
    a = mx; b = mn;
}
__device__ __forceinline__ void ce(u64& a, u64& b) {    // desc compare-exchange
    u64 mx = a > b ? a : b;
    u64 mn = a > b ? b : a;
    a = mx; b = mn;
}

// ---------- prep: convert x & Wk to fp8 e4m3 (unit scale), transpose Wg ----------
__global__ __launch_bounds__(256) void prep_kernel(
    const float* __restrict__ x, const float* __restrict__ Wk,
    const float* __restrict__ Wg,
    u8* __restrict__ x8, u8* __restrict__ wk8, float* __restrict__ WgT)
{
    __shared__ float t[32][33];
    const int bid = blockIdx.x;
    if (bid < 1024) {
        // fp8 conversion: segments of 16 floats -> 16 bytes
        const int gid = bid * 256 + threadIdx.x;
        const int NSX = BATCH * IN / 16;          // 524288
        const int NS  = NSX + HID * IN / 16;      // 1572864
        for (int s = gid; s < NS; s += 1024 * 256) {
            const float4* src; u8* dst;
            if (s < NSX) { src = (const float4*)x + (size_t)s * 4;  dst = x8  + (size_t)s * 16; }
            else { int u = s - NSX; src = (const float4*)Wk + (size_t)u * 4; dst = wk8 + (size_t)u * 16; }
            uint4 o;
            float4 f;
            int p;
            f = src[0];
            p = __builtin_amdgcn_cvt_pk_fp8_f32(f.x, f.y, 0, false);
            p = __builtin_amdgcn_cvt_pk_fp8_f32(f.z, f.w, p, true);  o.x = (u32)p;
            f = src[1];
            p = __builtin_amdgcn_cvt_pk_fp8_f32(f.x, f.y, 0, false);
            p = __builtin_amdgcn_cvt_pk_fp8_f32(f.z, f.w, p, true);  o.y = (u32)p;
            f = src[2];
            p = __builtin_amdgcn_cvt_pk_fp8_f32(f.x, f.y, 0, false);
            p = __builtin_amdgcn_cvt_pk_fp8_f32(f.z, f.w, p, true);  o.z = (u32)p;
            f = src[3];
            p = __builtin_amdgcn_cvt_pk_fp8_f32(f.x, f.y, 0, false);
            p = __builtin_amdgcn_cvt_pk_fp8_f32(f.z, f.w, p, true);  o.w = (u32)p;
            *(uint4*)dst = o;
        }
    } else {
        // Wg transpose tile
        const int tb = bid - 1024;
        const int bx = (tb & 255) * 32;   // HID
        const int by = (tb >> 8) * 32;    // NCLS
        const int tx = threadIdx.x & 31, ty = threadIdx.x >> 5;  // ty 0..7
        #pragma unroll
        for (int i = 0; i < 32; i += 8) {
            int c = by + ty + i;
            t[ty + i][tx] = (c < NCLS) ? Wg[(size_t)c * HID + bx + tx] : 0.f;
        }
        __syncthreads();
        #pragma unroll
        for (int i = 0; i < 32; i += 8) {
            int c = by + tx;
            if (c < NCLS) WgT[(size_t)(bx + ty + i) * NCLS + by + tx] = t[tx][ty + i];
        }
    }
}

// ---------- fp8 MFMA GEMM (16x16x128, unit scales): top-4 u32 keys / 64-col group ----------
// Structure identical to the round-6 kernel (which verified correct: absmax 0).
// Epilogue now uses u32 keys: (fkey(v) & ~0x3F) | (j<<4 | m). The 6 dropped
// mantissa bits cost ~0.002 absolute on scores (~26 sigma) — absorbed by the
// 12.0 screen margin. Sort network runs on v_max_u32/v_min_u32 (1 op per CE
// vs 3 for u64) — round-6's 48% VALUBusy was dominated by u64 key ops.
__global__ __launch_bounds__(256) void mfma_fp8_gemm_kernel(
    const u8* __restrict__ x8, const u8* __restrict__ wk8,
    u32* __restrict__ topk)
{
    __shared__ __align__(16) u8 At[128 * 128];   // 16 KB
    __shared__ __align__(16) u8 Bt[128 * 128];   // 16 KB

    const int tid  = threadIdx.x;
    const int lane = tid & 63;
    const int w    = tid >> 6;
    const int bm   = blockIdx.y * 128;
    const int bn   = blockIdx.x * 128;
    const int wrow = (w >> 1) * 64, wcol = (w & 1) * 64;
    const int m = lane & 15, q = lane >> 4;

    floatx4 acc[4][4];
    #pragma unroll
    for (int i = 0; i < 4; i++)
        #pragma unroll
        for (int j = 0; j < 4; j++)
            acc[i][j] = (floatx4){0.f, 0.f, 0.f, 0.f};

    // staging: lane covers row (tid>>3); source 16B-chunk permuted so that
    // physical chunk (tid&7) = logical granule ((tid>>1)&3)^(row&3), half (tid&1)
    const int srow = tid >> 3;
    const int soff = (((((tid >> 1) & 3) ^ (srow & 3)) * 2) + (tid & 1)) * 16;
    const u8* gxa = x8  + (size_t)(bm + srow) * IN + soff;
    const u8* gwb = wk8 + (size_t)(bn + srow) * IN + soff;

    // fragment read offset: logical granule q of row (..+m) sits at q^(m&3)
    const int foq = (q ^ (m & 3)) * 32;

    #pragma unroll 1
    for (int k0 = 0; k0 < IN; k0 += 128) {
        #pragma unroll
        for (int s = 0; s < 4; s++) {
            __builtin_amdgcn_global_load_lds(
                (const __attribute__((address_space(1))) u32*)(gxa + k0 + (size_t)s * 32 * IN),
                (__attribute__((address_space(3))) u32*)&At[s * 4096 + tid * 16], 16, 0, 0);
            __builtin_amdgcn_global_load_lds(
                (const __attribute__((address_space(1))) u32*)(gwb + k0 + (size_t)s * 32 * IN),
                (__attribute__((address_space(3))) u32*)&Bt[s * 4096 + tid * 16], 16, 0, 0);
        }
        __syncthreads();   // staging complete

        intx8 af[4];
        #pragma unroll
        for (int i = 0; i < 4; i++)
            af[i] = *(const intx8*)&At[(wrow + i * 16 + m) * 128 + foq];
        #pragma unroll
        for (int j = 0; j < 4; j++) {
            intx8 bf = *(const intx8*)&Bt[(wcol + j * 16 + m) * 128 + foq];
            #pragma unroll
            for (int i = 0; i < 4; i++)
                acc[i][j] = __builtin_amdgcn_mfma_scale_f32_16x16x128_f8f6f4(
                    af[i], bf, acc[i][j],
                    0, 0,            // cbsz=FP8(e4m3), blgp=FP8(e4m3)
                    0, 0x7F,         // opsel_a, scale_a = 2^0
                    0, 0x7F);        // opsel_b, scale_b = 2^0
        }

        __syncthreads();   // reads done before next overwrite
    }

    // epilogue: per-row top-4 (u32 keys) over this wave's 64 columns
    const int group = blockIdx.x * 2 + (wcol >> 6);   // 64-col group id, 0..127
    #pragma unroll
    for (int i = 0; i < 4; i++) {
        #pragma unroll
        for (int r = 0; r < 4; r++) {
            u32 k0 = (fkey(acc[i][0][r]) & 0xFFFFFFC0u) | (0u << 4) | (u32)m;
            u32 k1 = (fkey(acc[i][1][r]) & 0xFFFFFFC0u) | (1u << 4) | (u32)m;
            u32 k2 = (fkey(acc[i][2][r]) & 0xFFFFFFC0u) | (2u << 4) | (u32)m;
            u32 k3 = (fkey(acc[i][3][r]) & 0xFFFFFFC0u) | (3u << 4) | (u32)m;
            // sort 4 desc
            ce32(k0, k1); ce32(k2, k3); ce32(k0, k2); ce32(k1, k3); ce32(k1, k2);
            // butterfly top-4 merge over the 16 lanes sharing this row
            #pragma unroll
            for (int off = 1; off < 16; off <<= 1) {
                u32 b0 = __shfl_xor(k0, off, 64);
                u32 b1 = __shfl_xor(k1, off, 64);
                u32 b2 = __shfl_xor(k2, off, 64);
                u32 b3 = __shfl_xor(k3, off, 64);
                u32 t0 = k0 > b3 ? k0 : b3;    // bitonic keep-max
                u32 t1 = k1 > b2 ? k1 : b2;
                u32 t2 = k2 > b1 ? k2 : b1;
                u32 t3 = k3 > b0 ? k3 : b0;
                ce32(t0, t2); ce32(t1, t3); ce32(t0, t1); ce32(t2, t3);
                k0 = t0; k1 = t1; k2 = t2; k3 = t3;
            }
            if (m == 0) {
                const int grow = bm + wrow + i * 16 + q * 4 + r;
                uint4 v; v.x = k0; v.y = k1; v.z = k2; v.w = k3;
                *(uint4*)&topk[(size_t)grow * 512 + group * 4] = v;
            }
        }
    }
}

// ---------- scan: one WAVE per row; ballot compaction; exact rescore; gather ----------
__global__ __launch_bounds__(256) void scan_kernel(
    const u32* __restrict__ topk,
    const float* __restrict__ x, const float* __restrict__ Wk,
    const float* __restrict__ WgT, float* __restrict__ out)
{
    __shared__ u16 cand[4][48];
    const int wv   = threadIdx.x >> 6;
    const int lane = threadIdx.x & 63;
    const int row  = blockIdx.x * 4 + wv;

    const uint4* tp = (const uint4*)(topk + (size_t)row * 512);
    uint4 v0 = tp[lane];        // group = lane
    uint4 v1 = tp[lane + 64];   // group = lane + 64

    // row max (u32 keys are value-ordered; id bits only break near-ties)
    u32 mx = v0.x > v1.x ? v0.x : v1.x;   // slot 0 of each uint4 is its group's max
    #pragma unroll
    for (int off = 1; off < 64; off <<= 1) {
        u32 o = __shfl_xor(mx, off, 64);
        if (o > mx) mx = o;
    }
    const float thr = unfkey(mx & 0xFFFFFFC0u) - 12.0f;

    // ballot-compact in-window candidates into per-wave LDS (no atomics)
    int base = 0;
    const u32 ks[8] = {v0.x, v0.y, v0.z, v0.w, v1.x, v1.y, v1.z, v1.w};
    #pragma unroll
    for (int s = 0; s < 8; s++) {
        const int group = (s < 4) ? lane : (lane + 64);
        const u32 key = ks[s];
        const bool in = unfkey(key & 0xFFFFFFC0u) >= thr;
        const u64 msk = __ballot(in);
        if (in) {
            int rnk = base + __popcll(msk & ((1ull << lane) - 1ull));
            if (rnk < 48)
                cand[wv][rnk] = (u16)(group * 64 + (int)((key >> 4) & 3u) * 16 + (int)(key & 15u));
        }
        base += __popcll(msk);
    }
    const int n = min(base, 48);
    __builtin_amdgcn_wave_barrier();   // keep compiler from sinking LDS reads above writes

    int col;
    if (n <= 1) {
        col = cand[wv][0];   // the max itself is always in-window
    } else {
        // exact fp32 rescore, whole wave per candidate
        const float4* xr = (const float4*)(x + (size_t)row * IN);
        float4 a[8];
        #pragma unroll
        for (int p = 0; p < 8; p++) a[p] = xr[p * 64 + lane];
        u64 best = 0ull;
        for (int c = 0; c < n; c++) {
            const int h = cand[wv][c];
            const float4* wr = (const float4*)(Wk + (size_t)h * IN);
            float s = 0.f;
            #pragma unroll
            for (int p = 0; p < 8; p++) {
                float4 b = wr[p * 64 + lane];
                s += a[p].x * b.x + a[p].y * b.y + a[p].z * b.z + a[p].w * b.w;
            }
            #pragma unroll
            for (int off = 1; off < 64; off <<= 1) s += __shfl_xor(s, off, 64);
            // s identical on all lanes; track best on all lanes (no broadcast needed)
            u64 key = ((u64)fkey(s) << 32) | (u64)(0x1FFFu - (u32)h);  // smaller col wins ties
            if (key > best) best = key;
        }
        col = 0x1FFF - (int)(best & 0xFFFFu);
    }

    // gather: out[row, :] = WgT[col, :]   (both rows 16B-aligned: 1000*4 = 4000 B)
    const float4* src = (const float4*)(WgT + (size_t)col * NCLS);
    float4* dst = (float4*)(out + (size_t)row * NCLS);
    for (int t = lane; t < NCLS / 4; t += 64) dst[t] = src[t];
}

// ---------- round-1 fp32 fallback (used only if ws too small) ----------
__global__ void init_ws_kernel(u64* rowkey) {
    int i = blockIdx.x * blockDim.x + threadIdx.x;
    if (i < BATCH) rowkey[i] = 0ULL;
}

__global__ __launch_bounds__(256) void gemm_argmax_kernel(
    const float* __restrict__ x, const float* __restrict__ Wk,
    u64* __restrict__ rowkey)
{
    __shared__ __align__(16) float As[32 * 64];
    __shared__ __align__(16) float Bs[32 * 64];
    const int tid = threadIdx.x;
    const int bm = blockIdx.y * 64, bn = blockIdx.x * 64;
    const int tx = tid & 15, ty = tid >> 4;
    float acc[4][4];
    #pragma unroll
    for (int i = 0; i < 4; i++)
        #pragma unroll
        for (int j = 0; j < 4; j++) acc[i][j] = 0.f;
    const int r0 = tid >> 3, q0 = tid & 7;
    const int r1 = (tid + 256) >> 3, q1 = (tid + 256) & 7;
    const float* xA0 = &x[(size_t)(bm + r0) * IN + q0 * 4];
    const float* xA1 = &x[(size_t)(bm + r1) * IN + q1 * 4];
    const float* wB0 = &Wk[(size_t)(bn + r0) * IN + q0 * 4];
    const float* wB1 = &Wk[(size_t)(bn + r1) * IN + q1 * 4];
    for (int k0 = 0; k0 < IN; k0 += 32) {
        float4 a0 = *(const float4*)(xA0 + k0);
        float4 a1 = *(const float4*)(xA1 + k0);
        float4 b0 = *(const float4*)(wB0 + k0);
        float4 b1 = *(const float4*)(wB1 + k0);
        __syncthreads();
        As[(q0 * 4 + 0) * 64 + r0] = a0.x; As[(q0 * 4 + 1) * 64 + r0] = a0.y;
        As[(q0 * 4 + 2) * 64 + r0] = a0.z; As[(q0 * 4 + 3) * 64 + r0] = a0.w;
        As[(q1 * 4 + 0) * 64 + r1] = a1.x; As[(q1 * 4 + 1) * 64 + r1] = a1.y;
        As[(q1 * 4 + 2) * 64 + r1] = a1.z; As[(q1 * 4 + 3) * 64 + r1] = a1.w;
        Bs[(q0 * 4 + 0) * 64 + r0] = b0.x; Bs[(q0 * 4 + 1) * 64 + r0] = b0.y;
        Bs[(q0 * 4 + 2) * 64 + r0] = b0.z; Bs[(q0 * 4 + 3) * 64 + r0] = b0.w;
        Bs[(q1 * 4 + 0) * 64 + r1] = b1.x; Bs[(q1 * 4 + 1) * 64 + r1] = b1.y;
        Bs[(q1 * 4 + 2) * 64 + r1] = b1.z; Bs[(q1 * 4 + 3) * 64 + r1] = b1.w;
        __syncthreads();
        #pragma unroll
        for (int k = 0; k < 32; k++) {
            float4 av = *(const float4*)&As[k * 64 + ty * 4];
            float4 bv = *(const float4*)&Bs[k * 64 + tx * 4];
            acc[0][0] += av.x * bv.x; acc[0][1] += av.x * bv.y;
            acc[0][2] += av.x * bv.z; acc[0][3] += av.x * bv.w;
            acc[1][0] += av.y * bv.x; acc[1][1] += av.y * bv.y;
            acc[1][2] += av.y * bv.z; acc[1][3] += av.y * bv.w;
            acc[2][0] += av.z * bv.x; acc[2][1] += av.z * bv.y;
            acc[2][2] += av.z * bv.z; acc[2][3] += av.z * bv.w;
            acc[3][0] += av.w * bv.x; acc[3][1] += av.w * bv.y;
            acc[3][2] += av.w * bv.z; acc[3][3] += av.w * bv.w;
        }
    }
    #pragma unroll
    for (int i = 0; i < 4; i++) {
        const int row = bm + ty * 4 + i;
        u64 best = 0ULL;
        #pragma unroll
        for (int j = 0; j < 4; j++) {
            const int col = bn + tx * 4 + j;
            u64 p = ((u64)fkey(acc[i][j]) << 32) | (u64)(0x1FFFu - (unsigned)col);
            if (p > best) best = p;
        }
        #pragma unroll
        for (int off = 1; off < 16; off <<= 1) {
            u64 other = __shfl_xor(best, off, 64);
            if (other > best) best = other;
        }
        if (tx == 0) atomicMax(&rowkey[row], best);
    }
}

__global__ __launch_bounds__(256) void gather_kernel(
    const u64* __restrict__ rowkey, const float* __restrict__ Wg,
    float* __restrict__ out)
{
    const int b = blockIdx.y;
    const int c = blockIdx.x * 256 + threadIdx.x;
    if (c >= NCLS) return;
    const int col = 0x1FFF - (int)(rowkey[b] & 0xFFFFFFFFu);
    out[(size_t)b * NCLS + c] = Wg[(size_t)c * HID + col];
}

// ---------- launch ----------
extern "C" void kernel_launch(void* const* d_in, const int* in_sizes, int n_in,
                              void* d_out, int out_size, void* d_ws, size_t ws_size,
                              hipStream_t stream) {
    const float* x  = (const float*)d_in[0];
    const float* Wk = (const float*)d_in[1];
    const float* Wg = (const float*)d_in[2];
    float* out = (float*)d_out;
    char* ws = (char*)d_ws;

    if (ws_size >= TOTAL_FULL) {
        u32* topk  = (u32*)(ws + OFF_TOPK);
        u8*  x8    = (u8*)(ws + OFF_X8);
        u8*  wk8   = (u8*)(ws + OFF_WK8);
        float* WgT = (float*)(ws + OFF_WGT);

        hipLaunchKernelGGL(prep_kernel, dim3(1024 + 8192), dim3(256), 0, stream,
                           x, Wk, Wg, x8, wk8, WgT);
        hipLaunchKernelGGL(mfma_fp8_gemm_kernel, dim3(HID / 128, BATCH / 128), dim3(256), 0, stream,
                           x8, wk8, topk);
        hipLaunchKernelGGL(scan_kernel, dim3(BATCH / 4), dim3(256), 0, stream,
                           topk, x, Wk, WgT, out);
    } else {
        u64* rowkey = (u64*)(ws + OFF_ROWKEY);
        hipLaunchKernelGGL(init_ws_kernel, dim3(16), dim3(256), 0, stream, rowkey);
        hipLaunchKernelGGL(gemm_argmax_kernel, dim3(HID / 64, BATCH / 64), dim3(256), 0, stream,
                           x, Wk, rowkey);
        hipLaunchKernelGGL(gather_kernel, dim3(4, BATCH), dim3(256), 0, stream,
                           rowkey, Wg, out);
    }
}